// Round 3
// baseline (400.675 us; speedup 1.0000x reference)
//
#include <hip/hip_runtime.h>

typedef __attribute__((ext_vector_type(4))) int i32x4;
typedef __attribute__((ext_vector_type(16))) int i32x16;
typedef __attribute__((address_space(3))) char lds3;

#define D_IN  4096
#define D_OUT 4096
#define M_TOT 8192

// ---- async 16B global->LDS (wave-uniform base + lane*16 dest semantics) ----
__device__ __forceinline__ void async16(const void* g, lds3* l) {
  __builtin_amdgcn_global_load_lds(
      (__attribute__((address_space(1))) void*)g,
      (__attribute__((address_space(3))) void*)l,
      16, 0, 0);
}

// ds_read_b128 via inline asm: invisible to the compiler's waitcnt pass, so no
// auto "s_waitcnt vmcnt(0)" is inserted against outstanding global_load_lds.
#define DSR(dst, addr, off) \
  asm volatile("ds_read_b128 %0, %1 offset:%2" : "=v"(dst) : "v"(addr), "i"(off))

__device__ __forceinline__ int pack4(float a, float b, float c, float d, float s) {
  int q0 = (int)rintf(a * s) & 255;
  int q1 = (int)rintf(b * s) & 255;
  int q2 = (int)rintf(c * s) & 255;
  int q3 = (int)rintf(d * s) & 255;
  return q0 | (q1 << 8) | (q2 << 16) | (q3 << 24);
}

// ---- kernel 1: wave-per-row absmax quantize x -> int8, sx[row] = rowmax/127 ----
__global__ void quant_x_kernel(const float* __restrict__ x, int* __restrict__ xq,
                               float* __restrict__ sx) {
  const int row = blockIdx.x * 4 + (threadIdx.x >> 6);
  const int lane = threadIdx.x & 63;
  const float4* xr = (const float4*)(x + (size_t)row * D_IN);

  float4 v[16];
  float mx = 0.f;
#pragma unroll
  for (int j = 0; j < 16; j++) {
    v[j] = xr[j * 64 + lane];
    mx = fmaxf(mx, fmaxf(fmaxf(fabsf(v[j].x), fabsf(v[j].y)),
                         fmaxf(fabsf(v[j].z), fabsf(v[j].w))));
  }
#pragma unroll
  for (int off = 32; off; off >>= 1) mx = fmaxf(mx, __shfl_xor(mx, off));
  if (lane == 0) sx[row] = mx * (1.0f / 127.0f);

  const float inv = 127.0f / mx;
  int* xqr = xq + (size_t)row * (D_IN / 4);
#pragma unroll
  for (int j = 0; j < 16; j++)
    xqr[j * 64 + lane] = pack4(v[j].x, v[j].y, v[j].z, v[j].w, inv);
}

// ---- kernel 2: wave-per-row L2 norm (fp64 accum) + quantize W -> int8 ----
__global__ void quant_w_kernel(const float* __restrict__ W, int* __restrict__ wq,
                               float* __restrict__ sn) {
  const int row = blockIdx.x * 4 + (threadIdx.x >> 6);
  const int lane = threadIdx.x & 63;
  const float4* wr = (const float4*)(W + (size_t)row * D_IN);

  float4 v[16];
  double ss = 0.0;
#pragma unroll
  for (int j = 0; j < 16; j++) {
    v[j] = wr[j * 64 + lane];
    ss += (double)v[j].x * v[j].x + (double)v[j].y * v[j].y +
          (double)v[j].z * v[j].z + (double)v[j].w * v[j].w;
  }
#pragma unroll
  for (int off = 32; off; off >>= 1) ss += __shfl_xor(ss, off);
  const float nrm = (float)sqrt(ss);
  if (lane == 0) sn[row] = nrm * (1.0f / 127.0f);

  const float den = nrm + 1e-8f;
  int* wqr = wq + (size_t)row * (D_IN / 4);
#pragma unroll
  for (int j = 0; j < 16; j++) {
    float e[4] = {v[j].x, v[j].y, v[j].z, v[j].w};
    int q[4];
#pragma unroll
    for (int c = 0; c < 4; c++) {
      float wn = e[c] / den;
      wn = fminf(1.0f, fmaxf(-1.0f, wn));
      q[c] = (int)rintf(wn * 127.0f) & 255;
    }
    wqr[j * 64 + lane] = q[0] | (q[1] << 8) | (q[2] << 16) | (q[3] << 24);
  }
}

// ==== 256x256 i8 GEMM, 4 waves x (128x128 wave tile), BK=64 ==================
// 1 wave/SIMD: no cross-wave lockstep -> in-wave register pipelining works.
// LDS: 4 stages x (A 16K + B 16K) = 128 KiB; rows are 64 B (4 x 16B chunks);
// swizzle: stored chunk = c ^ ((row>>1)&3) -> 8 distinct bank-quads per
// 8-lane group on ds_read_b128. Staging keeps LDS dest linear, pre-swizzles
// the GLOBAL source chunk (involution). Per tile: {8 ds_read f0; issue next
// staging; lgkm; 8 ds_read f1; 16 MFMA(f0); lgkm; 16 MFMA(f1); vmcnt(16);
// barrier}. MFMA(f1)'s pipe tail covers the next tile's read burst, so the
// matrix pipe never drains. vmcnt never 0 until the tail.
#define MFMA16(F, acc) \
  _Pragma("unroll") \
  for (int mi = 0; mi < 4; mi++) \
    _Pragma("unroll") \
    for (int ni = 0; ni < 4; ni++) \
      acc[mi][ni] = __builtin_amdgcn_mfma_i32_32x32x32_i8(F[mi], F[4 + ni], acc[mi][ni], 0, 0, 0);

template<int S, int VM, bool ISSUE, bool SYNC>
__device__ __forceinline__ void ktile(unsigned aA0, unsigned aA1,
                                      unsigned aB0, unsigned aB1,
                                      const char* pA, const char* pB,
                                      lds3* lA, lds3* lB,
                                      i32x4 (&f0)[8], i32x4 (&f1)[8],
                                      i32x16 (&acc)[4][4]) {
  const unsigned tA0 = aA0 + S * 32768, tA1 = aA1 + S * 32768;
  const unsigned tB0 = aB0 + S * 32768, tB1 = aB1 + S * 32768;

  // slice 0 fragment reads (A: mi*2048 = 32 rows x 64 B; B: ni*2048)
  DSR(f0[0], tA0, 0);  DSR(f0[1], tA0, 2048);  DSR(f0[2], tA0, 4096);  DSR(f0[3], tA0, 6144);
  DSR(f0[4], tB0, 0);  DSR(f0[5], tB0, 2048);  DSR(f0[6], tB0, 4096);  DSR(f0[7], tB0, 6144);

  if (ISSUE) {   // stage (kt+3) into buffer (S+3)&3 (freed at last barrier)
    constexpr int T = ((S + 3) & 3) * 32768;
    async16(pA,                          lA + T);
    async16(pA + (size_t)64  * D_IN,     lA + T + 4096);
    async16(pA + (size_t)128 * D_IN,     lA + T + 8192);
    async16(pA + (size_t)192 * D_IN,     lA + T + 12288);
    async16(pB,                          lB + T);
    async16(pB + (size_t)64  * D_IN,     lB + T + 4096);
    async16(pB + (size_t)128 * D_IN,     lB + T + 8192);
    async16(pB + (size_t)192 * D_IN,     lB + T + 12288);
  }

  asm volatile("s_waitcnt lgkmcnt(0)"
               : "+v"(f0[0]), "+v"(f0[1]), "+v"(f0[2]), "+v"(f0[3]),
                 "+v"(f0[4]), "+v"(f0[5]), "+v"(f0[6]), "+v"(f0[7]));
  __builtin_amdgcn_sched_barrier(0);

  // slice 1 reads: latency hidden under MFMA(f0)
  DSR(f1[0], tA1, 0);  DSR(f1[1], tA1, 2048);  DSR(f1[2], tA1, 4096);  DSR(f1[3], tA1, 6144);
  DSR(f1[4], tB1, 0);  DSR(f1[5], tB1, 2048);  DSR(f1[6], tB1, 4096);  DSR(f1[7], tB1, 6144);
  __builtin_amdgcn_sched_barrier(0);

  MFMA16(f0, acc);
  __builtin_amdgcn_sched_barrier(0);

  asm volatile("s_waitcnt lgkmcnt(0)"
               : "+v"(f1[0]), "+v"(f1[1]), "+v"(f1[2]), "+v"(f1[3]),
                 "+v"(f1[4]), "+v"(f1[5]), "+v"(f1[6]), "+v"(f1[7]));
  __builtin_amdgcn_sched_barrier(0);

  MFMA16(f1, acc);

  if (SYNC) {
    __builtin_amdgcn_sched_barrier(0);
    asm volatile("s_waitcnt vmcnt(%0)" :: "i"(VM));   // stage kt+1 landed (mine)
    asm volatile("s_barrier" ::: "memory");           // ...published block-wide
  }
}

__global__ __launch_bounds__(256, 1)
void gemm_i8_kernel(const char* __restrict__ A, const char* __restrict__ B,
                    const float* __restrict__ sx, const float* __restrict__ sn,
                    const float* __restrict__ bias, float* __restrict__ C) {
  __shared__ __align__(16) char smem[131072];   // 4 stages x (A 16K | B 16K)

  const int t = threadIdx.x;                    // 256 threads = 4 waves
  const int lane = t & 63;
  const int wave = t >> 6;
  const int wm = wave >> 1, wn = wave & 1;      // 2M x 2N wave grid, 128x128 each

  // XCD-aware swizzle (512 wgs, 512%8==0 -> bijective)
  const int bid = blockIdx.x;
  const int swz = ((bid & 7) << 6) | (bid >> 3);
  const int m0 = (swz >> 4) * 256;              // 32 M-tiles
  const int n0 = (swz & 15) * 256;              // 16 N-tiles

  // staging: thread t covers row (call*64 + (t>>2)), chunk (t&3) of a 64-B row;
  // global source chunk pre-swizzled: sch = (t&3) ^ ((t>>3)&3); LDS dest linear.
  const int srow = t >> 2;
  const int sch  = (t & 3) ^ ((t >> 3) & 3);
  const char* gA = A + (size_t)(m0 + srow) * D_IN + sch * 16;
  const char* gB = B + (size_t)(n0 + srow) * D_IN + sch * 16;
  lds3* l3 = (lds3*)smem;
  lds3* lA = l3 + t * 16;
  lds3* lB = l3 + 16384 + t * 16;

  // fragment reads: row = wX*128 + mi|ni*32 + (lane&31), chunk c = kk*2 + (lane>>5),
  // stored slot = c ^ ((row>>1)&3) = c ^ (((lane&31)>>1)&3).
  const int l31 = lane & 31;
  const int hi  = lane >> 5;
  const int s3  = (l31 >> 1) & 3;
  const unsigned base = (unsigned)(size_t)l3;
  const unsigned aA0 = base + (wm * 128 + l31) * 64 + (unsigned)(((0 + hi) ^ s3) << 4);
  const unsigned aA1 = base + (wm * 128 + l31) * 64 + (unsigned)(((2 + hi) ^ s3) << 4);
  const unsigned aB0 = base + 16384 + (wn * 128 + l31) * 64 + (unsigned)(((0 + hi) ^ s3) << 4);
  const unsigned aB1 = base + 16384 + (wn * 128 + l31) * 64 + (unsigned)(((2 + hi) ^ s3) << 4);

  i32x16 acc[4][4];
#pragma unroll
  for (int i = 0; i < 4; i++)
#pragma unroll
    for (int j = 0; j < 4; j++) acc[i][j] = (i32x16)0;
  i32x4 f0[8], f1[8];

  // prologue: stage tiles 0,1,2 (issue order defines vmcnt counts: 8 per stage)
#pragma unroll
  for (int s = 0; s < 3; s++) {
    const char* qA = gA + s * 64;
    const char* qB = gB + s * 64;
    async16(qA,                      lA + s * 32768);
    async16(qA + (size_t)64  * D_IN, lA + s * 32768 + 4096);
    async16(qA + (size_t)128 * D_IN, lA + s * 32768 + 8192);
    async16(qA + (size_t)192 * D_IN, lA + s * 32768 + 12288);
    async16(qB,                      lB + s * 32768);
    async16(qB + (size_t)64  * D_IN, lB + s * 32768 + 4096);
    async16(qB + (size_t)128 * D_IN, lB + s * 32768 + 8192);
    async16(qB + (size_t)192 * D_IN, lB + s * 32768 + 12288);
  }
  asm volatile("s_waitcnt vmcnt(16)");     // stage 0 landed; 1,2 in flight
  asm volatile("s_barrier" ::: "memory");

  const char* pA = gA + 3 * 64;   // at tile kt: stages tile kt+3
  const char* pB = gB + 3 * 64;

#pragma unroll 1
  for (int it = 0; it < 15; ++it) {       // tiles 0..59
    ktile<0, 16, true, true>(aA0, aA1, aB0, aB1, pA, pB, lA, lB, f0, f1, acc); pA += 64; pB += 64;
    ktile<1, 16, true, true>(aA0, aA1, aB0, aB1, pA, pB, lA, lB, f0, f1, acc); pA += 64; pB += 64;
    ktile<2, 16, true, true>(aA0, aA1, aB0, aB1, pA, pB, lA, lB, f0, f1, acc); pA += 64; pB += 64;
    ktile<3, 16, true, true>(aA0, aA1, aB0, aB1, pA, pB, lA, lB, f0, f1, acc); pA += 64; pB += 64;
  }
  // tiles 60..63: tile 60 stages 63; then drain (VM: 16 -> 8 -> 0)
  ktile<0, 16, true,  true >(aA0, aA1, aB0, aB1, pA, pB, lA, lB, f0, f1, acc);
  ktile<1,  8, false, true >(aA0, aA1, aB0, aB1, pA, pB, lA, lB, f0, f1, acc);
  ktile<2,  0, false, true >(aA0, aA1, aB0, aB1, pA, pB, lA, lB, f0, f1, acc);
  ktile<3,  0, false, false>(aA0, aA1, aB0, aB1, pA, pB, lA, lB, f0, f1, acc);

  // epilogue: D layout (32x32): col = lane&31, row = (r&3) + 8*(r>>2) + 4*(lane>>5)
#pragma unroll
  for (int mi = 0; mi < 4; mi++) {
    const int rb = m0 + wm * 128 + mi * 32 + hi * 4;
    float sxv[16];
#pragma unroll
    for (int r = 0; r < 16; r++) sxv[r] = sx[rb + (r & 3) + 8 * (r >> 2)];
#pragma unroll
    for (int ni = 0; ni < 4; ni++) {
      const int col = n0 + wn * 128 + ni * 32 + l31;
      const float scn = sn[col];
      const float bv  = bias[col];
#pragma unroll
      for (int r = 0; r < 16; r++) {
        const int row = rb + (r & 3) + 8 * (r >> 2);
        C[(size_t)row * D_OUT + col] =
            (float)acc[mi][ni][r] * (sxv[r] * scn) + bv;
      }
    }
  }
}

extern "C" void kernel_launch(void* const* d_in, const int* in_sizes, int n_in,
                              void* d_out, int out_size, void* d_ws, size_t ws_size,
                              hipStream_t stream) {
  const float* x    = (const float*)d_in[0];   // [4,2048,4096]
  const float* W    = (const float*)d_in[1];   // [4096,4096]
  const float* bias = (const float*)d_in[2];   // [4096]
  float* out = (float*)d_out;                  // [4,2048,4096]

  char* ws = (char*)d_ws;
  char*  xq = ws;                                             // 33.5 MB int8
  char*  wq = ws + (size_t)M_TOT * D_IN;                      // 16.8 MB int8
  float* sx = (float*)(wq + (size_t)D_OUT * D_IN);
  float* sn = sx + M_TOT;

  quant_x_kernel<<<M_TOT / 4, 256, 0, stream>>>(x, (int*)xq, sx);
  quant_w_kernel<<<D_OUT / 4, 256, 0, stream>>>(W, (int*)wq, sn);
  gemm_i8_kernel<<<512, 256, 0, stream>>>(xq, wq, sx, sn, bias, out);
}

// Round 4
// 400.226 us; speedup vs baseline: 1.0011x; 1.0011x over previous
//
#include <hip/hip_runtime.h>

typedef __attribute__((ext_vector_type(4))) int i32x4;
typedef __attribute__((ext_vector_type(16))) int i32x16;
typedef unsigned long long ull;

#define D_IN  4096
#define D_OUT 4096
#define M_TOT 8192

__device__ __forceinline__ int pack4(float a, float b, float c, float d, float s) {
  int q0 = (int)rintf(a * s) & 255;
  int q1 = (int)rintf(b * s) & 255;
  int q2 = (int)rintf(c * s) & 255;
  int q3 = (int)rintf(d * s) & 255;
  return q0 | (q1 << 8) | (q2 << 16) | (q3 << 24);
}

// ==== fused quant + fragment-pack ===========================================
// Packed layout (matches mfma_i32_32x32x32_i8 operand layout, content identical
// to what the verified R3 LDS path delivered to each lane):
//   XP[mt][kt][l][b] = q( x[32*mt + (l&31)][32*kt + 16*(l>>5) + b] ),  b in [0,16)
// Block-per-row, 256 threads; thread t owns floats [16t, 16t+16) of its row,
// which is exactly fragment (kt = t>>1, half = t&1) -> one int4 store.
__global__ void quant_pack_kernel(const float* __restrict__ x, const float* __restrict__ W,
                                  char* __restrict__ XP, char* __restrict__ WP,
                                  float* __restrict__ sx, float* __restrict__ sn) {
  __shared__ float  redf[4];
  __shared__ double redd[4];
  __shared__ float  bc;
  const int bid = blockIdx.x, t = threadIdx.x;

  if (bid < M_TOT) {                    // ---- x path: absmax quant ----
    const int r = bid;
    const float4* xr = (const float4*)(x + (size_t)r * D_IN);
    float4 v[4];
    float mx = 0.f;
#pragma unroll
    for (int q = 0; q < 4; q++) {
      v[q] = xr[t * 4 + q];             // floats [16t+4q, +4)
      mx = fmaxf(mx, fmaxf(fmaxf(fabsf(v[q].x), fabsf(v[q].y)),
                           fmaxf(fabsf(v[q].z), fabsf(v[q].w))));
    }
#pragma unroll
    for (int off = 32; off; off >>= 1) mx = fmaxf(mx, __shfl_xor(mx, off));
    if ((t & 63) == 0) redf[t >> 6] = mx;
    __syncthreads();
    if (t == 0) {
      float m = fmaxf(fmaxf(redf[0], redf[1]), fmaxf(redf[2], redf[3]));
      bc = m;
      sx[r] = m * (1.0f / 127.0f);
    }
    __syncthreads();
    const float inv = 127.0f / bc;
    int4 o;
    o.x = pack4(v[0].x, v[0].y, v[0].z, v[0].w, inv);
    o.y = pack4(v[1].x, v[1].y, v[1].z, v[1].w, inv);
    o.z = pack4(v[2].x, v[2].y, v[2].z, v[2].w, inv);
    o.w = pack4(v[3].x, v[3].y, v[3].z, v[3].w, inv);
    const size_t addr =
        ((size_t)((r >> 5) * 128 + (t >> 1)) * 64 + (t & 1) * 32 + (r & 31)) * 16;
    *(int4*)(XP + addr) = o;
  } else {                              // ---- W path: L2-norm quant ----
    const int r = bid - M_TOT;
    const float4* wr = (const float4*)(W + (size_t)r * D_IN);
    float4 v[4];
    double ss = 0.0;
#pragma unroll
    for (int q = 0; q < 4; q++) {
      v[q] = wr[t * 4 + q];
      ss += (double)v[q].x * v[q].x + (double)v[q].y * v[q].y +
            (double)v[q].z * v[q].z + (double)v[q].w * v[q].w;
    }
#pragma unroll
    for (int off = 32; off; off >>= 1) ss += __shfl_xor(ss, off);
    if ((t & 63) == 0) redd[t >> 6] = ss;
    __syncthreads();
    if (t == 0) {
      double tot = redd[0] + redd[1] + redd[2] + redd[3];
      float nrm = (float)sqrt(tot);
      bc = nrm;
      sn[r] = nrm * (1.0f / 127.0f);
    }
    __syncthreads();
    const float den = bc + 1e-8f;
    int4 o;
    int* op = (int*)&o;
#pragma unroll
    for (int q = 0; q < 4; q++) {
      float e[4] = {v[q].x, v[q].y, v[q].z, v[q].w};
      int qq[4];
#pragma unroll
      for (int c = 0; c < 4; c++) {
        float wn = e[c] / den;
        wn = fminf(1.0f, fmaxf(-1.0f, wn));
        qq[c] = (int)rintf(wn * 127.0f) & 255;
      }
      op[q] = qq[0] | (qq[1] << 8) | (qq[2] << 16) | (qq[3] << 24);
    }
    const size_t addr =
        ((size_t)((r >> 5) * 128 + (t >> 1)) * 64 + (t & 1) * 32 + (r & 31)) * 16;
    *(int4*)(WP + addr) = o;
  }
}

// ==== flat i8 GEMM: fragment-direct loads, no LDS, no barriers ===============
// 512 blocks x 4 waves; wave tile 128x128 (block 256x256); BK=64 (2 MFMA
// k-slices). Per K-step each wave: 16 coalesced global_load_dwordx4 (next
// step's fragments) -> s_waitcnt vmcnt(16) (previous step landed) -> 32 MFMA.
// Loads overlap MFMAs on independent pipes; waves are fully independent.

#define GLD(dst, p, off) \
  asm volatile("global_load_dwordx4 %0, %1, off offset:%2" : "=v"(dst) : "v"(p), "i"(off))

__device__ __forceinline__ void load16(ull (&pa)[4], ull (&pb)[4],
                                       i32x4 (&fa)[8], i32x4 (&fb)[8]) {
#pragma unroll
  for (int mi = 0; mi < 4; mi++) {
    GLD(fa[2 * mi],     pa[mi], 0);
    GLD(fa[2 * mi + 1], pa[mi], 1024);
    pa[mi] += 2048;
  }
#pragma unroll
  for (int ni = 0; ni < 4; ni++) {
    GLD(fb[2 * ni],     pb[ni], 0);
    GLD(fb[2 * ni + 1], pb[ni], 1024);
    pb[ni] += 2048;
  }
}

template<int VM>
__device__ __forceinline__ void mfma32(i32x4 (&fa)[8], i32x4 (&fb)[8],
                                       i32x16 (&acc)[4][4]) {
  // wait for THESE fragments (issued one step earlier); tie regs through the
  // wait so MFMAs can't be hoisted above it (rule #18), then fence.
  asm volatile("s_waitcnt vmcnt(%[vm])"
               : "+v"(fa[0]), "+v"(fa[1]), "+v"(fa[2]), "+v"(fa[3]),
                 "+v"(fa[4]), "+v"(fa[5]), "+v"(fa[6]), "+v"(fa[7]),
                 "+v"(fb[0]), "+v"(fb[1]), "+v"(fb[2]), "+v"(fb[3]),
                 "+v"(fb[4]), "+v"(fb[5]), "+v"(fb[6]), "+v"(fb[7])
               : [vm] "i"(VM));
  __builtin_amdgcn_sched_barrier(0);
#pragma unroll
  for (int kk = 0; kk < 2; kk++)
#pragma unroll
    for (int mi = 0; mi < 4; mi++)
#pragma unroll
      for (int ni = 0; ni < 4; ni++)
        acc[mi][ni] = __builtin_amdgcn_mfma_i32_32x32x32_i8(
            fa[2 * mi + kk], fb[2 * ni + kk], acc[mi][ni], 0, 0, 0);
  __builtin_amdgcn_sched_barrier(0);
}

__global__ __launch_bounds__(256, 1)
void gemm_i8_kernel(const char* __restrict__ XP, const char* __restrict__ WP,
                    const float* __restrict__ sx, const float* __restrict__ sn,
                    const float* __restrict__ bias, float* __restrict__ C) {
  const int t = threadIdx.x;                 // 256 threads = 4 waves
  const int lane = t & 63;
  const int wave = t >> 6;
  const int wm = wave >> 1, wn = wave & 1;   // 2M x 2N, 128x128 per wave

  // XCD-aware map: each XCD owns 2 n-panels (2 MB of WP -> L2-resident) and
  // its two concurrent same-m blocks share the A panel (L2 hit). Bijective.
  const int bid = blockIdx.x;                // 512 = 32 m-blocks x 16 n-blocks
  const int xcd = bid & 7;
  const int j   = bid >> 3;                  // 0..63
  const int nblk = xcd * 2 + (j & 1);        // 0..15
  const int mblk = j >> 1;                   // 0..31
  const int m0 = mblk * 256, n0 = nblk * 256;

  // fragment base pointers: frag (mt, kt) lives at ((mt*128 + kt)*64 + lane)*16
  const int mt0 = (m0 >> 5) + wm * 4;
  const int nt0 = (n0 >> 5) + wn * 4;
  ull pa[4], pb[4];
#pragma unroll
  for (int mi = 0; mi < 4; mi++)
    pa[mi] = (ull)(XP + (size_t)(mt0 + mi) * 131072 + lane * 16);
#pragma unroll
  for (int ni = 0; ni < 4; ni++)
    pb[ni] = (ull)(WP + (size_t)(nt0 + ni) * 131072 + lane * 16);

  i32x16 acc[4][4];
#pragma unroll
  for (int i = 0; i < 4; i++)
#pragma unroll
    for (int jj = 0; jj < 4; jj++) acc[i][jj] = (i32x16)0;
  i32x4 fAa[8], fAb[8], fBa[8], fBb[8];      // ping-pong fragment buffers

  load16(pa, pb, fAa, fAb);                  // step 0
#pragma unroll 1
  for (int it = 0; it < 31; ++it) {          // steps 0..61 compute, 1..62 load
    load16(pa, pb, fBa, fBb);
    mfma32<16>(fAa, fAb, acc);
    load16(pa, pb, fAa, fAb);
    mfma32<16>(fBa, fBb, acc);
  }
  load16(pa, pb, fBa, fBb);                  // step 63 (last; no OOB prefetch)
  mfma32<16>(fAa, fAb, acc);                 // step 62
  mfma32<0>(fBa, fBb, acc);                  // step 63

  // epilogue: D layout (32x32): col = lane&31, row = (r&3) + 8*(r>>2) + 4*(lane>>5)
  const int l31 = lane & 31;
  const int hi  = lane >> 5;
#pragma unroll
  for (int mi = 0; mi < 4; mi++) {
    const int rbase = m0 + wm * 128 + mi * 32 + hi * 4;
    float sxv[16];
#pragma unroll
    for (int r = 0; r < 16; r++) sxv[r] = sx[rbase + (r & 3) + 8 * (r >> 2)];
#pragma unroll
    for (int ni = 0; ni < 4; ni++) {
      const int col = n0 + wn * 128 + ni * 32 + l31;
      const float scn = sn[col];
      const float bv  = bias[col];
#pragma unroll
      for (int r = 0; r < 16; r++) {
        const int row = rbase + (r & 3) + 8 * (r >> 2);
        C[(size_t)row * D_OUT + col] =
            (float)acc[mi][ni][r] * (sxv[r] * scn) + bv;
      }
    }
  }
}

extern "C" void kernel_launch(void* const* d_in, const int* in_sizes, int n_in,
                              void* d_out, int out_size, void* d_ws, size_t ws_size,
                              hipStream_t stream) {
  const float* x    = (const float*)d_in[0];   // [4,2048,4096]
  const float* W    = (const float*)d_in[1];   // [4096,4096]
  const float* bias = (const float*)d_in[2];   // [4096]
  float* out = (float*)d_out;                  // [4,2048,4096]

  char* ws = (char*)d_ws;
  char*  xp = ws;                                             // 33.5 MB packed i8
  char*  wp = ws + (size_t)M_TOT * D_IN;                      // 16.8 MB packed i8
  float* sx = (float*)(wp + (size_t)D_OUT * D_IN);
  float* sn = sx + M_TOT;

  quant_pack_kernel<<<M_TOT + D_OUT, 256, 0, stream>>>(x, W, xp, wp, sx, sn);
  gemm_i8_kernel<<<512, 256, 0, stream>>>(xp, wp, sx, sn, bias, out);
}

// Round 5
// 377.533 us; speedup vs baseline: 1.0613x; 1.0601x over previous
//
#include <hip/hip_runtime.h>

typedef __attribute__((ext_vector_type(4))) int i32x4;
typedef __attribute__((ext_vector_type(16))) int i32x16;
typedef unsigned long long ull;

#define D_IN  4096
#define D_OUT 4096
#define M_TOT 8192

// ==== fused quant + fragment-pack ===========================================
// Packed layout (unchanged from R4-verified):
//   piece (mt, kt, hi, l31) at mt*131072 + kt*1024 + hi*512 + l31*16
//   holds q(row 32mt+l31, k = 32kt+16hi .. +16)
// Producer: block = 16 rows (sub-half of an mt group), 512 threads, 8 waves.
// Wave w owns rows 2w, 2w+1: loads the WHOLE row into 64 float4 regs
// (fully coalesced), wave-local reduce (no syncthreads), quantize in-register,
// scatter int32s into a 64KB LDS image (XOR-swizzled -> 2-way, free), then one
// barrier and a fully-coalesced block store-out of the image (full lines).
__global__ __launch_bounds__(512, 4)
void quant_pack_kernel(const float* __restrict__ x, const float* __restrict__ W,
                       char* __restrict__ XP, char* __restrict__ WP,
                       float* __restrict__ sx, float* __restrict__ sn) {
  __shared__ __align__(16) char img[65536];   // [piece p<256][rl<16][16B], rl XOR-swizzled
  const int bid  = blockIdx.x;
  const int t    = threadIdx.x;
  const int lane = t & 63;
  const int wave = t >> 6;

  const bool isX = bid < (M_TOT / 16);
  const int  b2  = isX ? bid : bid - (M_TOT / 16);
  const float* src = isX ? x : W;
  char*  dst = isX ? XP : WP;
  float* sc  = isX ? sx : sn;

  // per-lane LDS write base: piece p = 16j + (lane>>2), slot = lane&3,
  // swizzled row: rl ^ (p&15) = rl ^ (lane>>2).
  const int g = lane >> 2, s4 = (lane & 3) << 2;

#pragma unroll
  for (int i = 0; i < 2; i++) {
    const int rl = wave * 2 + i;             // 0..15
    const int R  = b2 * 16 + rl;             // global row
    const float4* xr4 = (const float4*)(src + (size_t)R * D_IN);

    float4 v[16];
#pragma unroll
    for (int j = 0; j < 16; j++) v[j] = xr4[j * 64 + lane];   // coalesced 1KB/instr

    float inv;                               // multiplier: q = rint(v * inv), clamped for W
    if (isX) {
      float mx = 0.f;
#pragma unroll
      for (int j = 0; j < 16; j++)
        mx = fmaxf(mx, fmaxf(fmaxf(fabsf(v[j].x), fabsf(v[j].y)),
                             fmaxf(fabsf(v[j].z), fabsf(v[j].w))));
#pragma unroll
      for (int off = 32; off; off >>= 1) mx = fmaxf(mx, __shfl_xor(mx, off));
      if (lane == 0) sc[R] = mx * (1.0f / 127.0f);
      inv = 127.0f / mx;
      const unsigned wb = (unsigned)(g * 256 + ((rl ^ g) << 4) + s4);
      int* ip = (int*)(img + wb);
#pragma unroll
      for (int j = 0; j < 16; j++) {
        int q0 = (int)rintf(v[j].x * inv) & 255;
        int q1 = (int)rintf(v[j].y * inv) & 255;
        int q2 = (int)rintf(v[j].z * inv) & 255;
        int q3 = (int)rintf(v[j].w * inv) & 255;
        ip[j * 1024] = q0 | (q1 << 8) | (q2 << 16) | (q3 << 24);
      }
    } else {
      double ss = 0.0;
#pragma unroll
      for (int j = 0; j < 16; j++)
        ss += (double)v[j].x * v[j].x + (double)v[j].y * v[j].y +
              (double)v[j].z * v[j].z + (double)v[j].w * v[j].w;
#pragma unroll
      for (int off = 32; off; off >>= 1) ss += __shfl_xor(ss, off);
      const float nrm = (float)sqrt(ss);
      if (lane == 0) sc[R] = nrm * (1.0f / 127.0f);
      const float den = nrm + 1e-8f;
      const unsigned wb = (unsigned)(g * 256 + ((rl ^ g) << 4) + s4);
      int* ip = (int*)(img + wb);
#pragma unroll
      for (int j = 0; j < 16; j++) {
        float e[4] = {v[j].x, v[j].y, v[j].z, v[j].w};
        int q[4];
#pragma unroll
        for (int c = 0; c < 4; c++) {
          float wn = e[c] / den;
          wn = fminf(1.0f, fmaxf(-1.0f, wn));
          q[c] = (int)rintf(wn * 127.0f) & 255;
        }
        ip[j * 1024] = q[0] | (q[1] << 8) | (q[2] << 16) | (q[3] << 24);
      }
    }
  }

  __syncthreads();

  // store-out: 4096 chunks of 16B; chunk c -> piece p=c>>4, row rl=c&15.
  // Global: contiguous 256B runs at stride 512 (sub-halves interleave) = full lines.
  char* gbase = dst + (size_t)(b2 >> 1) * 131072 + (b2 & 1) * 256;
#pragma unroll
  for (int i = 0; i < 8; i++) {
    const int c  = t + 512 * i;
    const int p  = c >> 4;
    const int rl = c & 15;
    int4 val = *(const int4*)(img + p * 256 + ((rl ^ (p & 15)) << 4));
    *(int4*)(gbase + p * 512 + rl * 16) = val;
  }
}

// ==== flat i8 GEMM: fragment-direct loads, no LDS, no barriers ===============
// 512 blocks x 4 waves; wave tile 128x128 (block 256x256); BK=64.
// 3-deep fragment pipeline: loads for step s issued at s-2, vmcnt(32) steady
// (2 MFMA-phases + 2 load-phases of slack before each fragment's use).

#define GLD(dst, p, off) \
  asm volatile("global_load_dwordx4 %0, %1, off offset:%2" : "=v"(dst) : "v"(p), "i"(off))

__device__ __forceinline__ void load16(ull (&pa)[4], ull (&pb)[4],
                                       i32x4 (&fa)[8], i32x4 (&fb)[8]) {
#pragma unroll
  for (int mi = 0; mi < 4; mi++) {
    GLD(fa[2 * mi],     pa[mi], 0);
    GLD(fa[2 * mi + 1], pa[mi], 1024);
    pa[mi] += 2048;
  }
#pragma unroll
  for (int ni = 0; ni < 4; ni++) {
    GLD(fb[2 * ni],     pb[ni], 0);
    GLD(fb[2 * ni + 1], pb[ni], 1024);
    pb[ni] += 2048;
  }
}

template<int VM>
__device__ __forceinline__ void mfma32(i32x4 (&fa)[8], i32x4 (&fb)[8],
                                       i32x16 (&acc)[4][4]) {
  // wait for THESE fragments (issued two steps earlier); tie regs through the
  // wait so MFMAs can't be hoisted above it (rule #18), then fence.
  asm volatile("s_waitcnt vmcnt(%[vm])"
               : "+v"(fa[0]), "+v"(fa[1]), "+v"(fa[2]), "+v"(fa[3]),
                 "+v"(fa[4]), "+v"(fa[5]), "+v"(fa[6]), "+v"(fa[7]),
                 "+v"(fb[0]), "+v"(fb[1]), "+v"(fb[2]), "+v"(fb[3]),
                 "+v"(fb[4]), "+v"(fb[5]), "+v"(fb[6]), "+v"(fb[7])
               : [vm] "i"(VM));
  __builtin_amdgcn_sched_barrier(0);
#pragma unroll
  for (int kk = 0; kk < 2; kk++)
#pragma unroll
    for (int mi = 0; mi < 4; mi++)
#pragma unroll
      for (int ni = 0; ni < 4; ni++)
        acc[mi][ni] = __builtin_amdgcn_mfma_i32_32x32x32_i8(
            fa[2 * mi + kk], fb[2 * ni + kk], acc[mi][ni], 0, 0, 0);
  __builtin_amdgcn_sched_barrier(0);
}

__global__ __launch_bounds__(256, 1)
void gemm_i8_kernel(const char* __restrict__ XP, const char* __restrict__ WP,
                    const float* __restrict__ sx, const float* __restrict__ sn,
                    const float* __restrict__ bias, float* __restrict__ C) {
  const int t = threadIdx.x;                 // 256 threads = 4 waves
  const int lane = t & 63;
  const int wave = t >> 6;
  const int wm = wave >> 1, wn = wave & 1;   // 2M x 2N, 128x128 per wave

  // XCD-aware map: each XCD owns 2 n-panels (2 MB of WP -> L2-resident across
  // both rounds) and pairs same-m blocks for A reuse. Bijective.
  const int bid = blockIdx.x;                // 512 = 32 m-blocks x 16 n-blocks
  const int xcd = bid & 7;
  const int j   = bid >> 3;                  // 0..63
  const int nblk = xcd * 2 + (j & 1);        // 0..15
  const int mblk = j >> 1;                   // 0..31
  const int m0 = mblk * 256, n0 = nblk * 256;

  // fragment base pointers: frag (mt, kt) at ((mt*128 + kt)*64 + lane)*16
  const int mt0 = (m0 >> 5) + wm * 4;
  const int nt0 = (n0 >> 5) + wn * 4;
  ull pa[4], pb[4];
#pragma unroll
  for (int mi = 0; mi < 4; mi++)
    pa[mi] = (ull)(XP + (size_t)(mt0 + mi) * 131072 + lane * 16);
#pragma unroll
  for (int ni = 0; ni < 4; ni++)
    pb[ni] = (ull)(WP + (size_t)(nt0 + ni) * 131072 + lane * 16);

  i32x16 acc[4][4];
#pragma unroll
  for (int i = 0; i < 4; i++)
#pragma unroll
    for (int jj = 0; jj < 4; jj++) acc[i][jj] = (i32x16)0;
  i32x4 fAa[8], fAb[8], fBa[8], fBb[8], fCa[8], fCb[8];   // 3-deep pipeline

  load16(pa, pb, fAa, fAb);                  // s0
  load16(pa, pb, fBa, fBb);                  // s1
#pragma unroll 1
  for (int it = 0; it < 20; ++it) {          // computes s0..s59, loads s2..s61
    load16(pa, pb, fCa, fCb);
    mfma32<32>(fAa, fAb, acc);
    load16(pa, pb, fAa, fAb);
    mfma32<32>(fBa, fBb, acc);
    load16(pa, pb, fBa, fBb);
    mfma32<32>(fCa, fCb, acc);
  }
  load16(pa, pb, fCa, fCb);                  // s62
  mfma32<32>(fAa, fAb, acc);                 // s60
  load16(pa, pb, fAa, fAb);                  // s63 (last; no OOB prefetch)
  mfma32<32>(fBa, fBb, acc);                 // s61
  mfma32<16>(fCa, fCb, acc);                 // s62
  mfma32<0>(fAa, fAb, acc);                  // s63

  // epilogue: D layout (32x32): col = lane&31, row = (r&3) + 8*(r>>2) + 4*(lane>>5)
  const int l31 = lane & 31;
  const int hi  = lane >> 5;
#pragma unroll
  for (int mi = 0; mi < 4; mi++) {
    const int rbase = m0 + wm * 128 + mi * 32 + hi * 4;
    float sxv[16];
#pragma unroll
    for (int r = 0; r < 16; r++) sxv[r] = sx[rbase + (r & 3) + 8 * (r >> 2)];
#pragma unroll
    for (int ni = 0; ni < 4; ni++) {
      const int col = n0 + wn * 128 + ni * 32 + l31;
      const float scn = sn[col];
      const float bv  = bias[col];
#pragma unroll
      for (int r = 0; r < 16; r++) {
        const int row = rbase + (r & 3) + 8 * (r >> 2);
        C[(size_t)row * D_OUT + col] =
            (float)acc[mi][ni][r] * (sxv[r] * scn) + bv;
      }
    }
  }
}

extern "C" void kernel_launch(void* const* d_in, const int* in_sizes, int n_in,
                              void* d_out, int out_size, void* d_ws, size_t ws_size,
                              hipStream_t stream) {
  const float* x    = (const float*)d_in[0];   // [4,2048,4096]
  const float* W    = (const float*)d_in[1];   // [4096,4096]
  const float* bias = (const float*)d_in[2];   // [4096]
  float* out = (float*)d_out;                  // [4,2048,4096]

  char* ws = (char*)d_ws;
  char*  xp = ws;                                             // 33.5 MB packed i8
  char*  wp = ws + (size_t)M_TOT * D_IN;                      // 16.8 MB packed i8
  float* sx = (float*)(wp + (size_t)D_OUT * D_IN);
  float* sn = sx + M_TOT;

  quant_pack_kernel<<<(M_TOT + D_OUT) / 16, 512, 0, stream>>>(x, W, xp, wp, sx, sn);
  gemm_i8_kernel<<<512, 256, 0, stream>>>(xp, wp, sx, sn, bias, out);
}